// Round 8
// baseline (173.406 us; speedup 1.0000x reference)
//
#include <hip/hip_runtime.h>
#include <hip/hip_bf16.h>
#include <math.h>

// Problem constants (match reference)
#define BB   1024
#define MM   16
#define KK   32
#define LL   50
#define EE   64
#define NACT 100000

typedef __attribute__((ext_vector_type(8))) short short8;
typedef float v4f __attribute__((ext_vector_type(4)));

__device__ __forceinline__ float rcpf(float x) { return __builtin_amdgcn_rcpf(x); }

__device__ __forceinline__ float bf2f(short s) {
    unsigned u = ((unsigned)(unsigned short)s) << 16;
    return __builtin_bit_cast(float, u);
}
// packed f32x2 -> bf16x2 (lo->low16, hi->high16), RNE
__device__ __forceinline__ unsigned cvt_pk_bf16(float lo, float hi) {
    unsigned r;
    asm("v_cvt_pk_bf16_f32 %0, %1, %2" : "=v"(r) : "v"(lo), "v"(hi));
    return r;
}

// LDS-visibility sync that does NOT drain vmcnt (global prefetch loads stay
// in flight). With 1-wave blocks the s_barrier is trivially satisfied; the
// lgkmcnt(0) + sched fences give write->read ordering on own LDS.
__device__ __forceinline__ void block_sync_lds() {
    __builtin_amdgcn_sched_barrier(0);
    asm volatile("s_waitcnt lgkmcnt(0)" ::: "memory");
    __builtin_amdgcn_s_barrier();
    __builtin_amdgcn_sched_barrier(0);
}

// ---------------------------------------------------------------------------
// Pre-pass: act_table f32 -> bf16 (row-major, same layout). 8 floats/thread.
// ---------------------------------------------------------------------------
__global__ __launch_bounds__(256)
void cvt_table(const float* __restrict__ src, unsigned* __restrict__ dst)
{
    const int i = blockIdx.x * 256 + threadIdx.x;          // unit = 8 floats
    if (i < (NACT * EE) / 8) {
        const float4* s = reinterpret_cast<const float4*>(src) + (size_t)i * 2;
        float4 a = s[0], b = s[1];
        uint4 o;
        o.x = cvt_pk_bf16(a.x, a.y);
        o.y = cvt_pk_bf16(a.z, a.w);
        o.z = cvt_pk_bf16(b.x, b.y);
        o.w = cvt_pk_bf16(b.z, b.w);
        reinterpret_cast<uint4*>(dst)[i] = o;
    }
}

// ---------------------------------------------------------------------------
// Barrier-free MFMA LSTM: 1024 blocks x 64 threads (1 wave = 1 chain of 16
// sequences, ALL 256 gate columns). h redistribution is in-wave via a
// private 2 KB LDS tile + lgkmcnt(0) -- NO s_barrier dependency in the step
// loop; waves are fully independent (1 wave/SIMD, issue-bound by design).
// Full weights live in registers: 64 B-frags = 256 VGPR; total ~420 < 450
// spill boundary at 1 wave/SIMD (launch_bounds(64,1) allows 512).
// Bias folded into exp arguments; acc initialized from a shared zero vector.
// ---------------------------------------------------------------------------
__global__ __launch_bounds__(64, 1)
void lstm_wave(const int* __restrict__ act_seqs, const unsigned short* __restrict__ act_bf,
               const float* __restrict__ W_ih, const float* __restrict__ W_hh,
               const float* __restrict__ b_ih, const float* __restrict__ b_hh,
               float* __restrict__ m_act)
{
    __shared__ __align__(16) short sHt[16 * 64];   // h tile, bf16, swizzled (2 KB)
    __shared__ int sIdx[16 * LL];                  // 3.2 KB

    const int lane = threadIdx.x;   // 0..63
    const int blk  = blockIdx.x;    // 0..1023
    const int lr   = lane & 15;     // A row (seq) / B,D col selector
    const int lb   = lane >> 4;     // k-block / D row-block selector

    // --- this wave's indices (contiguous 800 ints)
    for (int i = lane; i < 16 * LL; i += 64) sIdx[i] = act_seqs[blk * (16 * LL) + i];

    // --- ALL weights -> register B-frags (2 mats x 4 gates x 4 e-blocks x 2 ks).
    // B[k][n]: lane holds col n = lr of tile (g,eb) => j = g*64 + eb*16 + lr,
    // k = 32*ks + 8*lb + i.
    short8 Bf[2][4][4][2];
    #pragma unroll
    for (int mat = 0; mat < 2; ++mat) {
        const float* W = mat ? W_hh : W_ih;
        #pragma unroll
        for (int g = 0; g < 4; ++g)
            #pragma unroll
            for (int eb = 0; eb < 4; ++eb) {
                const int j = g * 64 + eb * 16 + lr;
                #pragma unroll
                for (int ks = 0; ks < 2; ++ks) {
                    const float4* p = reinterpret_cast<const float4*>(&W[(size_t)j * 64 + ks * 32 + lb * 8]);
                    float4 v0 = p[0], v1 = p[1];
                    uint4 o;
                    o.x = cvt_pk_bf16(v0.x, v0.y);
                    o.y = cvt_pk_bf16(v0.z, v0.w);
                    o.z = cvt_pk_bf16(v1.x, v1.y);
                    o.w = cvt_pk_bf16(v1.z, v1.w);
                    Bf[mat][g][eb][ks] = __builtin_bit_cast(short8, o);
                }
            }
    }

    // --- bias, folded forms: sigma(acc+b) = rcp(1+exp(nb-acc)) with nb=-b;
    // tanh(acc+b) arg = 2*acc + tb with tb=2b.
    float nbI[4], nbF[4], tbG[4], nbO[4];
    #pragma unroll
    for (int eb = 0; eb < 4; ++eb) {
        const int base = eb * 16 + lr;
        nbI[eb] = -(b_ih[base] + b_hh[base]);
        nbF[eb] = -(b_ih[64 + base] + b_hh[64 + base]);
        tbG[eb] = 2.0f * (b_ih[128 + base] + b_hh[128 + base]);
        nbO[eb] = -(b_ih[192 + base] + b_hh[192 + base]);
    }

    float c[4][4];   // [eb][r]
    #pragma unroll
    for (int eb = 0; eb < 4; ++eb)
        #pragma unroll
        for (int r = 0; r < 4; ++r) c[eb][r] = 0.0f;

    // zero sHt (2048 B = 128 uint4)
    reinterpret_cast<uint4*>(sHt)[lane]      = make_uint4(0u, 0u, 0u, 0u);
    reinterpret_cast<uint4*>(sHt)[lane + 64] = make_uint4(0u, 0u, 0u, 0u);
    block_sync_lds();   // sIdx + zeroed tile visible

    // --- x gather: lane's frag = bytes [id*128 + lb*16] and +64.
    const char* tbl8 = reinterpret_cast<const char*>(act_bf) + lb * 16;
    const int idxbase = lr * LL;
    int idn = sIdx[idxbase + 0];
    short8 ax0 = *reinterpret_cast<const short8*>(tbl8 + (size_t)idn * 128);
    short8 ax1 = *reinterpret_cast<const short8*>(tbl8 + (size_t)idn * 128 + 64);
    idn = sIdx[idxbase + 1];

    // LDS byte offsets (loop-invariant). Reads: row lr, chunks lb / lb+4.
    const int offA0 = lr * 128 + ((lb ^ (lr & 7)) << 4);
    const int offA1 = lr * 128 + (((lb + 4) ^ (lr & 7)) << 4);
    int hw_off[4][4];   // write offsets for h(s=4lb+r, e=16eb+lr)
    #pragma unroll
    for (int eb = 0; eb < 4; ++eb)
        #pragma unroll
        for (int r = 0; r < 4; ++r) {
            const int s = lb * 4 + r, e = eb * 16 + lr;
            hw_off[eb][r] = s * 128 + ((((e >> 3) ^ (s & 7)) << 4)) + (e & 7) * 2;
        }
    char* const sHb = reinterpret_cast<char*>(sHt);

    const v4f z4 = {0.0f, 0.0f, 0.0f, 0.0f};

    for (int step = 0; step < LL; ++step) {
        // 1. read h A-frags (own tile, swizzled)
        short8 ah0 = *reinterpret_cast<const short8*>(sHb + offA0);
        short8 ah1 = *reinterpret_cast<const short8*>(sHb + offA1);

        // 2. gates = x @ Wih^T + h @ Whh^T  (16 tiles x 4 MFMA; bias folded later)
        v4f acc[4][4];
        #pragma unroll
        for (int g = 0; g < 4; ++g)
            #pragma unroll
            for (int eb = 0; eb < 4; ++eb) {
                v4f a = __builtin_amdgcn_mfma_f32_16x16x32_bf16(ax0, Bf[0][g][eb][0], z4, 0, 0, 0);
                a = __builtin_amdgcn_mfma_f32_16x16x32_bf16(ax1, Bf[0][g][eb][1], a, 0, 0, 0);
                a = __builtin_amdgcn_mfma_f32_16x16x32_bf16(ah0, Bf[1][g][eb][0], a, 0, 0, 0);
                a = __builtin_amdgcn_mfma_f32_16x16x32_bf16(ah1, Bf[1][g][eb][1], a, 0, 0, 0);
                acc[g][eb] = a;
            }

        // 3. issue x prefetch for step+1 (latency hides under nonlin)
        short8 nx0 = *reinterpret_cast<const short8*>(tbl8 + (size_t)idn * 128);
        short8 nx1 = *reinterpret_cast<const short8*>(tbl8 + (size_t)idn * 128 + 64);
        {
            const int s2 = (step + 2 < LL) ? (step + 2) : (LL - 1);
            idn = sIdx[idxbase + s2];
        }

        // 4. gate nonlinearities (i,f,g,o) + h writes, per e-block
        #pragma unroll
        for (int eb = 0; eb < 4; ++eb) {
            float hv[4];
            #pragma unroll
            for (int r = 0; r < 4; ++r) {
                const float si = rcpf(1.0f + __expf(nbI[eb] - acc[0][eb][r]));
                const float sf = rcpf(1.0f + __expf(nbF[eb] - acc[1][eb][r]));
                const float tg = fmaf(-2.0f, rcpf(1.0f + __expf(fmaf(2.0f, acc[2][eb][r], tbG[eb]))), 1.0f);
                const float so = rcpf(1.0f + __expf(nbO[eb] - acc[3][eb][r]));
                const float cc = fmaf(sf, c[eb][r], si * tg);
                c[eb][r] = cc;
                hv[r] = so * fmaf(-2.0f, rcpf(1.0f + __expf(cc + cc)), 1.0f);
            }
            const unsigned p01 = cvt_pk_bf16(hv[0], hv[1]);
            const unsigned p23 = cvt_pk_bf16(hv[2], hv[3]);
            *reinterpret_cast<short*>(sHb + hw_off[eb][0]) = (short)(p01 & 0xFFFF);
            *reinterpret_cast<short*>(sHb + hw_off[eb][1]) = (short)(p01 >> 16);
            *reinterpret_cast<short*>(sHb + hw_off[eb][2]) = (short)(p23 & 0xFFFF);
            *reinterpret_cast<short*>(sHb + hw_off[eb][3]) = (short)(p23 >> 16);
        }

        // 5. make h_t visible for step+1's reads (no vmcnt drain)
        block_sync_lds();
        ax0 = nx0; ax1 = nx1;
    }

    // --- final h -> m_act [16384][64] f32. Read back own tile as A-frags:
    // lane holds h[s=lr][e=8lb..8lb+7] and h[s=lr][e=32+8lb..+7].
    {
        short8 hf0 = *reinterpret_cast<const short8*>(sHb + offA0);
        short8 hf1 = *reinterpret_cast<const short8*>(sHb + offA1);
        float* orow = &m_act[((size_t)(blk * 16 + lr)) * EE];
        float4 o0, o1, o2, o3;
        o0.x = bf2f(hf0[0]); o0.y = bf2f(hf0[1]); o0.z = bf2f(hf0[2]); o0.w = bf2f(hf0[3]);
        o1.x = bf2f(hf0[4]); o1.y = bf2f(hf0[5]); o1.z = bf2f(hf0[6]); o1.w = bf2f(hf0[7]);
        o2.x = bf2f(hf1[0]); o2.y = bf2f(hf1[1]); o2.z = bf2f(hf1[2]); o2.w = bf2f(hf1[3]);
        o3.x = bf2f(hf1[4]); o3.y = bf2f(hf1[5]); o3.z = bf2f(hf1[6]); o3.w = bf2f(hf1[7]);
        *reinterpret_cast<float4*>(&orow[lb * 8])      = o0;
        *reinterpret_cast<float4*>(&orow[lb * 8 + 4])  = o1;
        *reinterpret_cast<float4*>(&orow[32 + lb * 8])     = o2;
        *reinterpret_cast<float4*>(&orow[32 + lb * 8 + 4]) = o3;
    }
}

// ---------------------------------------------------------------------------
// Kernel B: GCN gather + linear/relu + fuse + PNA reduce + MLPs + predict.
// One block per batch element b (1024 blocks x 256 threads). (unchanged)
// ---------------------------------------------------------------------------
__global__ __launch_bounds__(256)
void post_kernel(const int* __restrict__ members, const int* __restrict__ neighbors,
                 const int* __restrict__ act_inputs,
                 const float* __restrict__ act_table, const float* __restrict__ user_table,
                 const float* __restrict__ gcn_W, const float* __restrict__ gcn_b,
                 const float* __restrict__ pna_W1, const float* __restrict__ pna_b1,
                 const float* __restrict__ pna_W2, const float* __restrict__ pna_b2,
                 const float* __restrict__ pna_W3, const float* __restrict__ pna_b3,
                 const float* __restrict__ pred_W1, const float* __restrict__ pred_b1,
                 const float* __restrict__ pred_W2, const float* __restrict__ pred_b2,
                 const float* __restrict__ m_act, float* __restrict__ out)
{
    __shared__ float sWg[64][64];    // gcn_W transposed [k][e]
    __shared__ float sAgg[16][64];
    __shared__ float sFus[16][64];
    __shared__ float sActe[64];
    __shared__ float sFeats[256];
    __shared__ float sPart[4][64];
    __shared__ float sH1[64];
    __shared__ float sH2[64];
    __shared__ float sGrp[64];
    __shared__ float sHH[8];

    const int t  = threadIdx.x;
    const int b  = blockIdx.x;
    const int e  = t & 63;
    const int mq = t >> 6;   // 0..3 (wave id)

    {
        const int kq = (t & 15) * 4;
        const int er = t >> 4;   // 0..15
        #pragma unroll
        for (int rep = 0; rep < 4; ++rep) {
            int row = rep * 16 + er;
            float4 v = *reinterpret_cast<const float4*>(&gcn_W[row * 64 + kq]);
            sWg[kq + 0][row] = v.x;
            sWg[kq + 1][row] = v.y;
            sWg[kq + 2][row] = v.z;
            sWg[kq + 3][row] = v.w;
        }
    }
    if (t < 64) sActe[t] = act_table[(size_t)act_inputs[b] * EE + t];

    for (int mb = 0; mb < 4; ++mb) {
        int m = mb * 4 + mq;
        int base = b * MM + m;
        float s_ = user_table[(size_t)members[base] * EE + e];
        const int* nb = &neighbors[base * KK];
        #pragma unroll 4
        for (int kk = 0; kk < KK; ++kk)
            s_ += user_table[(size_t)nb[kk] * EE + e];
        sAgg[m][e] = s_ * (1.0f / 33.0f);
    }
    __syncthreads();

    for (int mb = 0; mb < 4; ++mb) {
        int m = mb * 4 + mq;
        float a = gcn_b[e];
        #pragma unroll
        for (int k = 0; k < 64; ++k) a = fmaf(sAgg[m][k], sWg[k][e], a);
        a = fmaxf(a, 0.0f);
        sFus[m][e] = m_act[((size_t)(b * MM + m)) * EE + e] + a;
    }
    __syncthreads();

    if (t < 64) {
        float mn = 0.0f, mx = -INFINITY;
        #pragma unroll
        for (int m = 0; m < MM; ++m) { float v = sFus[m][t]; mn += v; mx = fmaxf(mx, v); }
        mn *= (1.0f / 16.0f);
        sFeats[t] = mn; sFeats[64 + t] = mx; sFeats[128 + t] = mn; sFeats[192 + t] = mx;
    }
    __syncthreads();

    {
        float p = 0.0f;
        #pragma unroll 8
        for (int kk = 0; kk < 64; ++kk) {
            int k = mq * 64 + kk;
            p = fmaf(sFeats[k], pna_W1[(size_t)k * 64 + e], p);
        }
        sPart[mq][e] = p;
    }
    __syncthreads();
    if (t < 64) sH1[t] = fmaxf(pna_b1[t] + sPart[0][t] + sPart[1][t] + sPart[2][t] + sPart[3][t], 0.0f);
    __syncthreads();

    {
        float p = 0.0f;
        #pragma unroll
        for (int kk = 0; kk < 16; ++kk) {
            int k = mq * 16 + kk;
            p = fmaf(sH1[k], pna_W2[(size_t)k * 64 + e], p);
        }
        sPart[mq][e] = p;
    }
    __syncthreads();
    if (t < 64) sH2[t] = fmaxf(pna_b2[t] + sPart[0][t] + sPart[1][t] + sPart[2][t] + sPart[3][t], 0.0f);
    __syncthreads();

    {
        float p = 0.0f;
        #pragma unroll
        for (int kk = 0; kk < 16; ++kk) {
            int k = mq * 16 + kk;
            p = fmaf(sH2[k], pna_W3[(size_t)k * 64 + e], p);
        }
        sPart[mq][e] = p;
    }
    __syncthreads();
    if (t < 64) sGrp[t] = pna_b3[t] + sPart[0][t] + sPart[1][t] + sPart[2][t] + sPart[3][t];
    __syncthreads();

    if (t < 8) {
        float a = pred_b1[t];
        for (int k = 0; k < 192; ++k) {
            float cv = (k < 64) ? sGrp[k] * sActe[k]
                                : ((k < 128) ? sGrp[k - 64] : sActe[k - 128]);
            a = fmaf(cv, pred_W1[k * 8 + t], a);
        }
        sHH[t] = fmaxf(a, 0.0f);
    }
    __syncthreads();
    if (t == 0) {
        float y = pred_b2[0];
        #pragma unroll
        for (int j = 0; j < 8; ++j) y = fmaf(sHH[j], pred_W2[j], y);
        out[b] = 1.0f / (1.0f + expf(-y));
    }
}

extern "C" void kernel_launch(void* const* d_in, const int* in_sizes, int n_in,
                              void* d_out, int out_size, void* d_ws, size_t ws_size,
                              hipStream_t stream) {
    const int*   members    = (const int*)d_in[0];
    const int*   neighbors  = (const int*)d_in[1];
    const int*   act_inputs = (const int*)d_in[2];
    const int*   act_seqs   = (const int*)d_in[3];
    const float* act_table  = (const float*)d_in[4];
    const float* user_table = (const float*)d_in[5];
    const float* W_ih       = (const float*)d_in[6];
    const float* W_hh       = (const float*)d_in[7];
    const float* b_ih       = (const float*)d_in[8];
    const float* b_hh       = (const float*)d_in[9];
    const float* gcn_W      = (const float*)d_in[10];
    const float* gcn_b      = (const float*)d_in[11];
    const float* pna_W1     = (const float*)d_in[12];
    const float* pna_b1     = (const float*)d_in[13];
    const float* pna_W2     = (const float*)d_in[14];
    const float* pna_b2     = (const float*)d_in[15];
    const float* pna_W3     = (const float*)d_in[16];
    const float* pna_b3     = (const float*)d_in[17];
    const float* pred_W1    = (const float*)d_in[18];
    const float* pred_b1    = (const float*)d_in[19];
    const float* pred_W2    = (const float*)d_in[20];
    const float* pred_b2    = (const float*)d_in[21];

    float*          m_act  = (float*)d_ws;                         // 4 MB
    unsigned short* act_bf = (unsigned short*)((char*)d_ws + (size_t)BB * MM * EE * 4);  // 12.8 MB

    cvt_table<<<dim3((NACT * EE / 8 + 255) / 256), dim3(256), 0, stream>>>(
        act_table, (unsigned*)act_bf);

    lstm_wave<<<dim3(1024), dim3(64), 0, stream>>>(
        act_seqs, act_bf, W_ih, W_hh, b_ih, b_hh, m_act);

    post_kernel<<<dim3(BB), dim3(256), 0, stream>>>(
        members, neighbors, act_inputs, act_table, user_table,
        gcn_W, gcn_b, pna_W1, pna_b1, pna_W2, pna_b2, pna_W3, pna_b3,
        pred_W1, pred_b1, pred_W2, pred_b2, m_act, (float*)d_out);
}

// Round 9
// 153.335 us; speedup vs baseline: 1.1309x; 1.1309x over previous
//
#include <hip/hip_runtime.h>
#include <hip/hip_bf16.h>
#include <math.h>

// Problem constants (match reference)
#define BB   1024
#define MM   16
#define KK   32
#define LL   50
#define EE   64
#define NACT 100000

typedef __attribute__((ext_vector_type(8))) short short8;
typedef float v4f __attribute__((ext_vector_type(4)));

__device__ __forceinline__ float rcpf(float x) { return __builtin_amdgcn_rcpf(x); }
// native 2^x (v_exp_f32 IS exp2)
__device__ __forceinline__ float exp2_fast(float x) {
    float r;
    asm("v_exp_f32 %0, %1" : "=v"(r) : "v"(x));
    return r;
}

// packed f32x2 -> bf16x2 (lo->low16, hi->high16), RNE
__device__ __forceinline__ unsigned cvt_pk_bf16(float lo, float hi) {
    unsigned r;
    asm("v_cvt_pk_bf16_f32 %0, %1, %2" : "=v"(r) : "v"(lo), "v"(hi));
    return r;
}

// Block-wide barrier that does NOT drain vmcnt: LDS writes are made visible
// (lgkmcnt(0)) but global prefetch loads stay in flight across the barrier.
__device__ __forceinline__ void block_sync_lds() {
    __builtin_amdgcn_sched_barrier(0);
    asm volatile("s_waitcnt lgkmcnt(0)" ::: "memory");
    __builtin_amdgcn_s_barrier();
    __builtin_amdgcn_sched_barrier(0);
}

// ---------------------------------------------------------------------------
// Pre-pass: act_table f32 -> bf16 (row-major, same layout). 8 floats/thread.
// ---------------------------------------------------------------------------
__global__ __launch_bounds__(256)
void cvt_table(const float* __restrict__ src, unsigned* __restrict__ dst)
{
    const int i = blockIdx.x * 256 + threadIdx.x;          // unit = 8 floats
    if (i < (NACT * EE) / 8) {
        const float4* s = reinterpret_cast<const float4*>(src) + (size_t)i * 2;
        float4 a = s[0], b = s[1];
        uint4 o;
        o.x = cvt_pk_bf16(a.x, a.y);
        o.y = cvt_pk_bf16(a.z, a.w);
        o.z = cvt_pk_bf16(b.x, b.y);
        o.w = cvt_pk_bf16(b.z, b.w);
        reinterpret_cast<uint4*>(dst)[i] = o;
    }
}

// ---------------------------------------------------------------------------
// MFMA LSTM: 1024 blocks x 256 threads; 16 seqs/block; 1 chain/wave.
// Target 3 blocks/CU (12 waves/CU, 3 waves/SIMD) -- the three co-resident
// blocks have independent barriers, so barrier waits overlap across blocks.
// exp2-folding: weight columns & biases pre-scaled by -log2e (i,f,o) and
// +2*log2e (g) so MFMA output feeds v_exp_f32 (=2^x) directly:
//   sigma(pre) = rcp(1+exp2(acc)),  tanh(pre) = 1-2*rcp(1+exp2(acc)).
// Weights in registers (64 VGPR); h via swizzled bf16 LDS double buffer;
// x A-frags prefetched from bf16 table, left in flight across the barrier.
// ---------------------------------------------------------------------------
__global__ __launch_bounds__(256, 3)
void lstm_mfma(const int* __restrict__ act_seqs, const unsigned short* __restrict__ act_bf,
               const float* __restrict__ W_ih, const float* __restrict__ W_hh,
               const float* __restrict__ b_ih, const float* __restrict__ b_hh,
               float* __restrict__ m_act)
{
    __shared__ __align__(16) short sH[2][16 * 64];   // h double buffer (bf16, swizzled)
    __shared__ int sIdx[16 * LL];

    const int t    = threadIdx.x;
    const int blk  = blockIdx.x;
    const int lane = t & 63;
    const int w    = t >> 6;        // wave id = e-block (0..3)
    const int lr   = lane & 15;     // A row (seq) / B,D col selector
    const int lb   = lane >> 4;     // k-block / D row-block selector

    // --- this block's indices (contiguous 800 ints, coalesced)
    for (int i = t; i < 16 * LL; i += 256) sIdx[i] = act_seqs[blk * (16 * LL) + i];

    // per-gate exp2 fold scales (i,f,o: -log2e; g: +2*log2e)
    const float L2E = 1.44269504088896f;
    float gscale[4];
    gscale[0] = -L2E; gscale[1] = -L2E; gscale[2] = 2.0f * L2E; gscale[3] = -L2E;

    // --- weights -> register B-frags, SCALED. gates = in @ W^T => B[k][j]=W[j][k].
    // lane holds col j = g*64 + 16w + lr, k = 32*ks + 8*lb + i.
    short8 Bf[2][4][2];   // [mat(ih,hh)][gate][ks]
    #pragma unroll
    for (int mat = 0; mat < 2; ++mat) {
        const float* W = mat ? W_hh : W_ih;
        #pragma unroll
        for (int g = 0; g < 4; ++g) {
            const int j = g * 64 + w * 16 + lr;
            const float sc = gscale[g];
            #pragma unroll
            for (int ks = 0; ks < 2; ++ks) {
                const float4* p = reinterpret_cast<const float4*>(&W[(size_t)j * 64 + ks * 32 + lb * 8]);
                float4 v0 = p[0], v1 = p[1];
                uint4 o;
                o.x = cvt_pk_bf16(sc * v0.x, sc * v0.y);
                o.y = cvt_pk_bf16(sc * v0.z, sc * v0.w);
                o.z = cvt_pk_bf16(sc * v1.x, sc * v1.y);
                o.w = cvt_pk_bf16(sc * v1.z, sc * v1.w);
                Bf[mat][g][ks] = __builtin_bit_cast(short8, o);
            }
        }
    }
    float bias[4];
    #pragma unroll
    for (int g = 0; g < 4; ++g) {
        const int j = g * 64 + w * 16 + lr;
        bias[g] = gscale[g] * (b_ih[j] + b_hh[j]);
    }

    float h[4], c[4];
    #pragma unroll
    for (int r = 0; r < 4; ++r) { h[r] = 0.0f; c[r] = 0.0f; }

    // zero sH[0] (2048 shorts = 256 x uint2)
    reinterpret_cast<uint2*>(sH[0])[t] = make_uint2(0u, 0u);
    __syncthreads();   // sIdx + sH[0] visible (once, outside loop)

    // --- x gather: lane's frag = bytes [id*128 + lb*16] and +64.
    const char* tbl8 = reinterpret_cast<const char*>(act_bf) + lb * 16;
    const int idxbase = lr * LL;
    int idn = sIdx[idxbase + 0];
    short8 ax0 = *reinterpret_cast<const short8*>(tbl8 + (size_t)idn * 128);
    short8 ax1 = *reinterpret_cast<const short8*>(tbl8 + (size_t)idn * 128 + 64);
    idn = sIdx[idxbase + 1];

    // LDS byte offsets (loop-invariant)
    const int offA0 = lr * 128 + ((lb ^ (lr & 7)) << 4);
    const int offA1 = lr * 128 + (((lb + 4) ^ (lr & 7)) << 4);
    int hw_off[4];
    #pragma unroll
    for (int r = 0; r < 4; ++r) {
        const int s = lb * 4 + r, e = w * 16 + lr;
        hw_off[r] = s * 128 + ((((e >> 3) ^ (s & 7)) << 4)) + (e & 7) * 2;
    }
    char* const sHb = reinterpret_cast<char*>(sH[0]);

    for (int step = 0; step < LL; ++step) {
        const int curoff = (step & 1) << 11;   // 0 or 2048

        // 1. issue x prefetch for step+1 (stays in flight across the barrier)
        short8 nx0 = *reinterpret_cast<const short8*>(tbl8 + (size_t)idn * 128);
        short8 nx1 = *reinterpret_cast<const short8*>(tbl8 + (size_t)idn * 128 + 64);
        {
            const int s2 = (step + 2 < LL) ? (step + 2) : (LL - 1);
            idn = sIdx[idxbase + s2];
        }

        // 2. read h A-frags (swizzled, conflict-free)
        const char* bh = sHb + curoff;
        short8 ah0 = *reinterpret_cast<const short8*>(bh + offA0);
        short8 ah1 = *reinterpret_cast<const short8*>(bh + offA1);

        // 3. acc = scaled_bias + x @ sWih^T + h @ sWhh^T
        v4f acc[4];
        #pragma unroll
        for (int g = 0; g < 4; ++g) {
            v4f a; a[0] = bias[g]; a[1] = bias[g]; a[2] = bias[g]; a[3] = bias[g];
            acc[g] = a;
        }
        #pragma unroll
        for (int g = 0; g < 4; ++g)
            acc[g] = __builtin_amdgcn_mfma_f32_16x16x32_bf16(ax0, Bf[0][g][0], acc[g], 0, 0, 0);
        #pragma unroll
        for (int g = 0; g < 4; ++g)
            acc[g] = __builtin_amdgcn_mfma_f32_16x16x32_bf16(ax1, Bf[0][g][1], acc[g], 0, 0, 0);
        #pragma unroll
        for (int g = 0; g < 4; ++g)
            acc[g] = __builtin_amdgcn_mfma_f32_16x16x32_bf16(ah0, Bf[1][g][0], acc[g], 0, 0, 0);
        #pragma unroll
        for (int g = 0; g < 4; ++g)
            acc[g] = __builtin_amdgcn_mfma_f32_16x16x32_bf16(ah1, Bf[1][g][1], acc[g], 0, 0, 0);

        // 4. gate nonlinearities (i,f,g,o): exp2 args come straight from MFMA
        #pragma unroll
        for (int r = 0; r < 4; ++r) {
            const float si = rcpf(1.0f + exp2_fast(acc[0][r]));
            const float sf = rcpf(1.0f + exp2_fast(acc[1][r]));
            const float tg = fmaf(-2.0f, rcpf(1.0f + exp2_fast(acc[2][r])), 1.0f);
            const float so = rcpf(1.0f + exp2_fast(acc[3][r]));
            const float cc = fmaf(sf, c[r], si * tg);
            c[r] = cc;
            h[r] = so * fmaf(-2.0f, rcpf(1.0f + exp2_fast(cc * (2.0f * L2E))), 1.0f);
        }

        // 5. write h_t into the NEXT buffer (packed converts, 4x b16 stores)
        {
            char* SH = sHb + (curoff ^ 2048);
            const unsigned p01 = cvt_pk_bf16(h[0], h[1]);
            const unsigned p23 = cvt_pk_bf16(h[2], h[3]);
            *reinterpret_cast<short*>(SH + hw_off[0]) = (short)(p01 & 0xFFFF);
            *reinterpret_cast<short*>(SH + hw_off[1]) = (short)(p01 >> 16);
            *reinterpret_cast<short*>(SH + hw_off[2]) = (short)(p23 & 0xFFFF);
            *reinterpret_cast<short*>(SH + hw_off[3]) = (short)(p23 >> 16);
        }

        // 6. LDS-only barrier (x prefetch loads stay in flight)
        block_sync_lds();
        ax0 = nx0; ax1 = nx1;
    }

    // --- write final h -> m_act [16384][64] f32
    #pragma unroll
    for (int r = 0; r < 4; ++r) {
        const int s = lb * 4 + r;
        m_act[((size_t)(blk * 16 + s)) * EE + w * 16 + lr] = h[r];
    }
}

// ---------------------------------------------------------------------------
// Kernel B: GCN gather + linear/relu + fuse + PNA reduce + MLPs + predict.
// One block per batch element b (1024 blocks x 256 threads). (unchanged)
// ---------------------------------------------------------------------------
__global__ __launch_bounds__(256)
void post_kernel(const int* __restrict__ members, const int* __restrict__ neighbors,
                 const int* __restrict__ act_inputs,
                 const float* __restrict__ act_table, const float* __restrict__ user_table,
                 const float* __restrict__ gcn_W, const float* __restrict__ gcn_b,
                 const float* __restrict__ pna_W1, const float* __restrict__ pna_b1,
                 const float* __restrict__ pna_W2, const float* __restrict__ pna_b2,
                 const float* __restrict__ pna_W3, const float* __restrict__ pna_b3,
                 const float* __restrict__ pred_W1, const float* __restrict__ pred_b1,
                 const float* __restrict__ pred_W2, const float* __restrict__ pred_b2,
                 const float* __restrict__ m_act, float* __restrict__ out)
{
    __shared__ float sWg[64][64];    // gcn_W transposed [k][e]
    __shared__ float sAgg[16][64];
    __shared__ float sFus[16][64];
    __shared__ float sActe[64];
    __shared__ float sFeats[256];
    __shared__ float sPart[4][64];
    __shared__ float sH1[64];
    __shared__ float sH2[64];
    __shared__ float sGrp[64];
    __shared__ float sHH[8];

    const int t  = threadIdx.x;
    const int b  = blockIdx.x;
    const int e  = t & 63;
    const int mq = t >> 6;   // 0..3 (wave id)

    {
        const int kq = (t & 15) * 4;
        const int er = t >> 4;   // 0..15
        #pragma unroll
        for (int rep = 0; rep < 4; ++rep) {
            int row = rep * 16 + er;
            float4 v = *reinterpret_cast<const float4*>(&gcn_W[row * 64 + kq]);
            sWg[kq + 0][row] = v.x;
            sWg[kq + 1][row] = v.y;
            sWg[kq + 2][row] = v.z;
            sWg[kq + 3][row] = v.w;
        }
    }
    if (t < 64) sActe[t] = act_table[(size_t)act_inputs[b] * EE + t];

    for (int mb = 0; mb < 4; ++mb) {
        int m = mb * 4 + mq;
        int base = b * MM + m;
        float s_ = user_table[(size_t)members[base] * EE + e];
        const int* nb = &neighbors[base * KK];
        #pragma unroll 4
        for (int kk = 0; kk < KK; ++kk)
            s_ += user_table[(size_t)nb[kk] * EE + e];
        sAgg[m][e] = s_ * (1.0f / 33.0f);
    }
    __syncthreads();

    for (int mb = 0; mb < 4; ++mb) {
        int m = mb * 4 + mq;
        float a = gcn_b[e];
        #pragma unroll
        for (int k = 0; k < 64; ++k) a = fmaf(sAgg[m][k], sWg[k][e], a);
        a = fmaxf(a, 0.0f);
        sFus[m][e] = m_act[((size_t)(b * MM + m)) * EE + e] + a;
    }
    __syncthreads();

    if (t < 64) {
        float mn = 0.0f, mx = -INFINITY;
        #pragma unroll
        for (int m = 0; m < MM; ++m) { float v = sFus[m][t]; mn += v; mx = fmaxf(mx, v); }
        mn *= (1.0f / 16.0f);
        sFeats[t] = mn; sFeats[64 + t] = mx; sFeats[128 + t] = mn; sFeats[192 + t] = mx;
    }
    __syncthreads();

    {
        float p = 0.0f;
        #pragma unroll 8
        for (int kk = 0; kk < 64; ++kk) {
            int k = mq * 64 + kk;
            p = fmaf(sFeats[k], pna_W1[(size_t)k * 64 + e], p);
        }
        sPart[mq][e] = p;
    }
    __syncthreads();
    if (t < 64) sH1[t] = fmaxf(pna_b1[t] + sPart[0][t] + sPart[1][t] + sPart[2][t] + sPart[3][t], 0.0f);
    __syncthreads();

    {
        float p = 0.0f;
        #pragma unroll
        for (int kk = 0; kk < 16; ++kk) {
            int k = mq * 16 + kk;
            p = fmaf(sH1[k], pna_W2[(size_t)k * 64 + e], p);
        }
        sPart[mq][e] = p;
    }
    __syncthreads();
    if (t < 64) sH2[t] = fmaxf(pna_b2[t] + sPart[0][t] + sPart[1][t] + sPart[2][t] + sPart[3][t], 0.0f);
    __syncthreads();

    {
        float p = 0.0f;
        #pragma unroll
        for (int kk = 0; kk < 16; ++kk) {
            int k = mq * 16 + kk;
            p = fmaf(sH2[k], pna_W3[(size_t)k * 64 + e], p);
        }
        sPart[mq][e] = p;
    }
    __syncthreads();
    if (t < 64) sGrp[t] = pna_b3[t] + sPart[0][t] + sPart[1][t] + sPart[2][t] + sPart[3][t];
    __syncthreads();

    if (t < 8) {
        float a = pred_b1[t];
        for (int k = 0; k < 192; ++k) {
            float cv = (k < 64) ? sGrp[k] * sActe[k]
                                : ((k < 128) ? sGrp[k - 64] : sActe[k - 128]);
            a = fmaf(cv, pred_W1[k * 8 + t], a);
        }
        sHH[t] = fmaxf(a, 0.0f);
    }
    __syncthreads();
    if (t == 0) {
        float y = pred_b2[0];
        #pragma unroll
        for (int j = 0; j < 8; ++j) y = fmaf(sHH[j], pred_W2[j], y);
        out[b] = 1.0f / (1.0f + expf(-y));
    }
}

extern "C" void kernel_launch(void* const* d_in, const int* in_sizes, int n_in,
                              void* d_out, int out_size, void* d_ws, size_t ws_size,
                              hipStream_t stream) {
    const int*   members    = (const int*)d_in[0];
    const int*   neighbors  = (const int*)d_in[1];
    const int*   act_inputs = (const int*)d_in[2];
    const int*   act_seqs   = (const int*)d_in[3];
    const float* act_table  = (const float*)d_in[4];
    const float* user_table = (const float*)d_in[5];
    const float* W_ih       = (const float*)d_in[6];
    const float* W_hh       = (const float*)d_in[7];
    const float* b_ih       = (const float*)d_in[8];
    const float* b_hh       = (const float*)d_in[9];
    const float* gcn_W      = (const float*)d_in[10];
    const float* gcn_b      = (const float*)d_in[11];
    const float* pna_W1     = (const float*)d_in[12];
    const float* pna_b1     = (const float*)d_in[13];
    const float* pna_W2     = (const float*)d_in[14];
    const float* pna_b2     = (const float*)d_in[15];
    const float* pna_W3     = (const float*)d_in[16];
    const float* pna_b3     = (const float*)d_in[17];
    const float* pred_W1    = (const float*)d_in[18];
    const float* pred_b1    = (const float*)d_in[19];
    const float* pred_W2    = (const float*)d_in[20];
    const float* pred_b2    = (const float*)d_in[21];

    float*          m_act  = (float*)d_ws;                         // 4 MB
    unsigned short* act_bf = (unsigned short*)((char*)d_ws + (size_t)BB * MM * EE * 4);  // 12.8 MB

    cvt_table<<<dim3((NACT * EE / 8 + 255) / 256), dim3(256), 0, stream>>>(
        act_table, (unsigned*)act_bf);

    lstm_mfma<<<dim3(1024), dim3(256), 0, stream>>>(
        act_seqs, act_bf, W_ih, W_hh, b_ih, b_hh, m_act);

    post_kernel<<<dim3(BB), dim3(256), 0, stream>>>(
        members, neighbors, act_inputs, act_table, user_table,
        gcn_W, gcn_b, pna_W1, pna_b1, pna_W2, pna_b2, pna_W3, pna_b3,
        pred_W1, pred_b1, pred_W2, pred_b2, m_act, (float*)d_out);
}

// Round 10
// 143.320 us; speedup vs baseline: 1.2099x; 1.0699x over previous
//
#include <hip/hip_runtime.h>
#include <hip/hip_bf16.h>
#include <math.h>

// Problem constants (match reference)
#define BB   1024
#define MM   16
#define KK   32
#define LL   50
#define EE   64
#define NACT 100000

typedef __attribute__((ext_vector_type(8))) short short8;
typedef float v4f __attribute__((ext_vector_type(4)));

__device__ __forceinline__ float rcpf(float x) { return __builtin_amdgcn_rcpf(x); }
// native 2^x (v_exp_f32 IS exp2)
__device__ __forceinline__ float exp2_fast(float x) {
    float r;
    asm("v_exp_f32 %0, %1" : "=v"(r) : "v"(x));
    return r;
}

// packed f32x2 -> bf16x2 (lo->low16, hi->high16), RNE
__device__ __forceinline__ unsigned cvt_pk_bf16(float lo, float hi) {
    unsigned r;
    asm("v_cvt_pk_bf16_f32 %0, %1, %2" : "=v"(r) : "v"(lo), "v"(hi));
    return r;
}

// Block-wide barrier that does NOT drain vmcnt: LDS writes are made visible
// (lgkmcnt(0)) but global prefetch loads stay in flight across the barrier.
__device__ __forceinline__ void block_sync_lds() {
    __builtin_amdgcn_sched_barrier(0);
    asm volatile("s_waitcnt lgkmcnt(0)" ::: "memory");
    __builtin_amdgcn_s_barrier();
    __builtin_amdgcn_sched_barrier(0);
}

// ---------------------------------------------------------------------------
// Pre-pass: act_table f32 -> bf16 (row-major, same layout). 8 floats/thread.
// ---------------------------------------------------------------------------
__global__ __launch_bounds__(256)
void cvt_table(const float* __restrict__ src, unsigned* __restrict__ dst)
{
    const int i = blockIdx.x * 256 + threadIdx.x;          // unit = 8 floats
    if (i < (NACT * EE) / 8) {
        const float4* s = reinterpret_cast<const float4*>(src) + (size_t)i * 2;
        float4 a = s[0], b = s[1];
        uint4 o;
        o.x = cvt_pk_bf16(a.x, a.y);
        o.y = cvt_pk_bf16(a.z, a.w);
        o.z = cvt_pk_bf16(b.x, b.y);
        o.w = cvt_pk_bf16(b.z, b.w);
        reinterpret_cast<uint4*>(dst)[i] = o;
    }
}

// ---------------------------------------------------------------------------
// MFMA LSTM, dual-chain + exp2 fold (union of r7 and r9's proven wins):
// 512 blocks x 256 threads; 32 seqs/block as two independent 16-seq chains
// per wave (2x ILP inside each wave -- r7's win). Weight columns & biases
// pre-scaled by -log2e (i,f,o) / +2*log2e (g) so MFMA output feeds
// v_exp_f32 (=2^x) directly (r9's win):
//   sigma(pre) = rcp(1+exp2(acc)),  tanh(pre) = 1-2*rcp(1+exp2(acc)).
// Weights in registers (64 VGPR); h via swizzled bf16 LDS double buffer;
// x A-frags prefetched top-of-step, left in flight across the non-draining
// barrier; step loop unrolled 2x to eliminate buffer-roll v_movs.
// ---------------------------------------------------------------------------
__global__ __launch_bounds__(256, 2)
void lstm_mfma(const int* __restrict__ act_seqs, const unsigned short* __restrict__ act_bf,
               const float* __restrict__ W_ih, const float* __restrict__ W_hh,
               const float* __restrict__ b_ih, const float* __restrict__ b_hh,
               float* __restrict__ m_act)
{
    __shared__ __align__(16) short sH[4][1024];   // tile = buf*2 + chain; [16][64] bf16 swizzled
    __shared__ int sIdx[32 * LL];

    const int t    = threadIdx.x;
    const int blk  = blockIdx.x;
    const int lane = t & 63;
    const int w    = t >> 6;        // wave id = e-block (0..3)
    const int lr   = lane & 15;     // A row (seq) / B,D col selector
    const int lb   = lane >> 4;     // k-block / D row-block selector

    // --- this block's indices (contiguous 1600 ints, coalesced)
    for (int i = t; i < 32 * LL; i += 256) sIdx[i] = act_seqs[blk * (32 * LL) + i];

    // per-gate exp2 fold scales (i,f,o: -log2e; g: +2*log2e)
    const float L2E = 1.44269504088896f;
    float gscale[4];
    gscale[0] = -L2E; gscale[1] = -L2E; gscale[2] = 2.0f * L2E; gscale[3] = -L2E;

    // --- weights -> register B-frags, SCALED. gates = in @ W^T => B[k][j]=W[j][k].
    // lane holds col j = g*64 + 16w + lr, k = 32*ks + 8*lb + i.
    short8 Bf[2][4][2];   // [mat(ih,hh)][gate][ks]
    #pragma unroll
    for (int mat = 0; mat < 2; ++mat) {
        const float* W = mat ? W_hh : W_ih;
        #pragma unroll
        for (int g = 0; g < 4; ++g) {
            const int j = g * 64 + w * 16 + lr;
            const float sc = gscale[g];
            #pragma unroll
            for (int ks = 0; ks < 2; ++ks) {
                const float4* p = reinterpret_cast<const float4*>(&W[(size_t)j * 64 + ks * 32 + lb * 8]);
                float4 v0 = p[0], v1 = p[1];
                uint4 o;
                o.x = cvt_pk_bf16(sc * v0.x, sc * v0.y);
                o.y = cvt_pk_bf16(sc * v0.z, sc * v0.w);
                o.z = cvt_pk_bf16(sc * v1.x, sc * v1.y);
                o.w = cvt_pk_bf16(sc * v1.z, sc * v1.w);
                Bf[mat][g][ks] = __builtin_bit_cast(short8, o);
            }
        }
    }
    float bias[4];
    #pragma unroll
    for (int g = 0; g < 4; ++g) {
        const int j = g * 64 + w * 16 + lr;
        bias[g] = gscale[g] * (b_ih[j] + b_hh[j]);
    }

    float hA[4], cA[4], hB[4], cB[4];
    #pragma unroll
    for (int r = 0; r < 4; ++r) { hA[r] = 0.0f; cA[r] = 0.0f; hB[r] = 0.0f; cB[r] = 0.0f; }

    // zero buf0 (tiles 0,1 = 4096 B = 256 x uint4)
    reinterpret_cast<uint4*>(sH)[t] = make_uint4(0u, 0u, 0u, 0u);
    __syncthreads();   // sIdx + sH buf0 visible (once, outside loop)

    // --- x gather: lane's frag = bytes [id*128 + lb*16] and +64.
    const char* tbl8 = reinterpret_cast<const char*>(act_bf) + lb * 16;
    const int ibA = lr * LL;           // chain A: seq lr
    const int ibB = (16 + lr) * LL;    // chain B: seq 16+lr

    int idA = sIdx[ibA + 0], idB = sIdx[ibB + 0];
    short8 axA0 = *reinterpret_cast<const short8*>(tbl8 + (size_t)idA * 128);
    short8 axA1 = *reinterpret_cast<const short8*>(tbl8 + (size_t)idA * 128 + 64);
    short8 axB0 = *reinterpret_cast<const short8*>(tbl8 + (size_t)idB * 128);
    short8 axB1 = *reinterpret_cast<const short8*>(tbl8 + (size_t)idB * 128 + 64);
    idA = sIdx[ibA + 1]; idB = sIdx[ibB + 1];

    // LDS byte offsets (loop-invariant)
    const int offA0 = lr * 128 + ((lb ^ (lr & 7)) << 4);
    const int offA1 = lr * 128 + (((lb + 4) ^ (lr & 7)) << 4);
    int hw_off[4];
    #pragma unroll
    for (int r = 0; r < 4; ++r) {
        const int s = lb * 4 + r, e = w * 16 + lr;
        hw_off[r] = s * 128 + ((((e >> 3) ^ (s & 7)) << 4)) + (e & 7) * 2;
    }
    char* const sHb = reinterpret_cast<char*>(sH);

    #pragma unroll 2
    for (int step = 0; step < LL; ++step) {
        const int cb  = (step & 1) << 12;   // current buf base: 0 or 4096
        const int nb_ = cb ^ 4096;          // next buf base

        // 1. issue x prefetch for step+1 (stays in flight across the barrier)
        short8 nxA0 = *reinterpret_cast<const short8*>(tbl8 + (size_t)idA * 128);
        short8 nxA1 = *reinterpret_cast<const short8*>(tbl8 + (size_t)idA * 128 + 64);
        short8 nxB0 = *reinterpret_cast<const short8*>(tbl8 + (size_t)idB * 128);
        short8 nxB1 = *reinterpret_cast<const short8*>(tbl8 + (size_t)idB * 128 + 64);
        {
            const int s2 = (step + 2 < LL) ? (step + 2) : (LL - 1);
            idA = sIdx[ibA + s2]; idB = sIdx[ibB + s2];
        }

        // 2. read h A-frags for both chains (swizzled, conflict-free)
        short8 ahA0 = *reinterpret_cast<const short8*>(sHb + cb + offA0);
        short8 ahA1 = *reinterpret_cast<const short8*>(sHb + cb + offA1);
        short8 ahB0 = *reinterpret_cast<const short8*>(sHb + cb + 2048 + offA0);
        short8 ahB1 = *reinterpret_cast<const short8*>(sHb + cb + 2048 + offA1);

        // 3. acc = scaled_bias + x @ sWih^T + h @ sWhh^T  (2 independent chains)
        v4f accA[4], accB[4];
        #pragma unroll
        for (int g = 0; g < 4; ++g) {
            v4f a; a[0] = bias[g]; a[1] = bias[g]; a[2] = bias[g]; a[3] = bias[g];
            accA[g] = a; accB[g] = a;
        }
        #pragma unroll
        for (int g = 0; g < 4; ++g) {
            accA[g] = __builtin_amdgcn_mfma_f32_16x16x32_bf16(axA0, Bf[0][g][0], accA[g], 0, 0, 0);
            accA[g] = __builtin_amdgcn_mfma_f32_16x16x32_bf16(axA1, Bf[0][g][1], accA[g], 0, 0, 0);
            accA[g] = __builtin_amdgcn_mfma_f32_16x16x32_bf16(ahA0, Bf[1][g][0], accA[g], 0, 0, 0);
            accA[g] = __builtin_amdgcn_mfma_f32_16x16x32_bf16(ahA1, Bf[1][g][1], accA[g], 0, 0, 0);
        }
        #pragma unroll
        for (int g = 0; g < 4; ++g) {
            accB[g] = __builtin_amdgcn_mfma_f32_16x16x32_bf16(axB0, Bf[0][g][0], accB[g], 0, 0, 0);
            accB[g] = __builtin_amdgcn_mfma_f32_16x16x32_bf16(axB1, Bf[0][g][1], accB[g], 0, 0, 0);
            accB[g] = __builtin_amdgcn_mfma_f32_16x16x32_bf16(ahB0, Bf[1][g][0], accB[g], 0, 0, 0);
            accB[g] = __builtin_amdgcn_mfma_f32_16x16x32_bf16(ahB1, Bf[1][g][1], accB[g], 0, 0, 0);
        }

        // 4. gate nonlinearities (exp2 args straight from MFMA) + h writes
        {
            char* SH = sHb + nb_;
            #pragma unroll
            for (int r = 0; r < 4; ++r) {
                const float si = rcpf(1.0f + exp2_fast(accA[0][r]));
                const float sf = rcpf(1.0f + exp2_fast(accA[1][r]));
                const float tg = fmaf(-2.0f, rcpf(1.0f + exp2_fast(accA[2][r])), 1.0f);
                const float so = rcpf(1.0f + exp2_fast(accA[3][r]));
                const float cc = fmaf(sf, cA[r], si * tg);
                cA[r] = cc;
                hA[r] = so * fmaf(-2.0f, rcpf(1.0f + exp2_fast(cc * (2.0f * L2E))), 1.0f);
            }
            const unsigned a01 = cvt_pk_bf16(hA[0], hA[1]);
            const unsigned a23 = cvt_pk_bf16(hA[2], hA[3]);
            *reinterpret_cast<short*>(SH + hw_off[0]) = (short)(a01 & 0xFFFF);
            *reinterpret_cast<short*>(SH + hw_off[1]) = (short)(a01 >> 16);
            *reinterpret_cast<short*>(SH + hw_off[2]) = (short)(a23 & 0xFFFF);
            *reinterpret_cast<short*>(SH + hw_off[3]) = (short)(a23 >> 16);
            SH += 2048;
            #pragma unroll
            for (int r = 0; r < 4; ++r) {
                const float si = rcpf(1.0f + exp2_fast(accB[0][r]));
                const float sf = rcpf(1.0f + exp2_fast(accB[1][r]));
                const float tg = fmaf(-2.0f, rcpf(1.0f + exp2_fast(accB[2][r])), 1.0f);
                const float so = rcpf(1.0f + exp2_fast(accB[3][r]));
                const float cc = fmaf(sf, cB[r], si * tg);
                cB[r] = cc;
                hB[r] = so * fmaf(-2.0f, rcpf(1.0f + exp2_fast(cc * (2.0f * L2E))), 1.0f);
            }
            const unsigned b01 = cvt_pk_bf16(hB[0], hB[1]);
            const unsigned b23 = cvt_pk_bf16(hB[2], hB[3]);
            *reinterpret_cast<short*>(SH + hw_off[0]) = (short)(b01 & 0xFFFF);
            *reinterpret_cast<short*>(SH + hw_off[1]) = (short)(b01 >> 16);
            *reinterpret_cast<short*>(SH + hw_off[2]) = (short)(b23 & 0xFFFF);
            *reinterpret_cast<short*>(SH + hw_off[3]) = (short)(b23 >> 16);
        }

        // 5. LDS-only barrier (x prefetch loads stay in flight)
        block_sync_lds();

        // 6. roll prefetch regs (unroll-2 lets the allocator rename these)
        axA0 = nxA0; axA1 = nxA1; axB0 = nxB0; axB1 = nxB1;
    }

    // --- write final h -> m_act [16384][64] f32 (chain A then B)
    #pragma unroll
    for (int r = 0; r < 4; ++r) {
        const int s = lb * 4 + r;
        m_act[((size_t)(blk * 32 + s)) * EE + w * 16 + lr]      = hA[r];
        m_act[((size_t)(blk * 32 + 16 + s)) * EE + w * 16 + lr] = hB[r];
    }
}

// ---------------------------------------------------------------------------
// Kernel B: GCN gather + linear/relu + fuse + PNA reduce + MLPs + predict.
// One block per batch element b (1024 blocks x 256 threads). (unchanged)
// ---------------------------------------------------------------------------
__global__ __launch_bounds__(256)
void post_kernel(const int* __restrict__ members, const int* __restrict__ neighbors,
                 const int* __restrict__ act_inputs,
                 const float* __restrict__ act_table, const float* __restrict__ user_table,
                 const float* __restrict__ gcn_W, const float* __restrict__ gcn_b,
                 const float* __restrict__ pna_W1, const float* __restrict__ pna_b1,
                 const float* __restrict__ pna_W2, const float* __restrict__ pna_b2,
                 const float* __restrict__ pna_W3, const float* __restrict__ pna_b3,
                 const float* __restrict__ pred_W1, const float* __restrict__ pred_b1,
                 const float* __restrict__ pred_W2, const float* __restrict__ pred_b2,
                 const float* __restrict__ m_act, float* __restrict__ out)
{
    __shared__ float sWg[64][64];    // gcn_W transposed [k][e]
    __shared__ float sAgg[16][64];
    __shared__ float sFus[16][64];
    __shared__ float sActe[64];
    __shared__ float sFeats[256];
    __shared__ float sPart[4][64];
    __shared__ float sH1[64];
    __shared__ float sH2[64];
    __shared__ float sGrp[64];
    __shared__ float sHH[8];

    const int t  = threadIdx.x;
    const int b  = blockIdx.x;
    const int e  = t & 63;
    const int mq = t >> 6;   // 0..3 (wave id)

    {
        const int kq = (t & 15) * 4;
        const int er = t >> 4;   // 0..15
        #pragma unroll
        for (int rep = 0; rep < 4; ++rep) {
            int row = rep * 16 + er;
            float4 v = *reinterpret_cast<const float4*>(&gcn_W[row * 64 + kq]);
            sWg[kq + 0][row] = v.x;
            sWg[kq + 1][row] = v.y;
            sWg[kq + 2][row] = v.z;
            sWg[kq + 3][row] = v.w;
        }
    }
    if (t < 64) sActe[t] = act_table[(size_t)act_inputs[b] * EE + t];

    for (int mb = 0; mb < 4; ++mb) {
        int m = mb * 4 + mq;
        int base = b * MM + m;
        float s_ = user_table[(size_t)members[base] * EE + e];
        const int* nb = &neighbors[base * KK];
        #pragma unroll 4
        for (int kk = 0; kk < KK; ++kk)
            s_ += user_table[(size_t)nb[kk] * EE + e];
        sAgg[m][e] = s_ * (1.0f / 33.0f);
    }
    __syncthreads();

    for (int mb = 0; mb < 4; ++mb) {
        int m = mb * 4 + mq;
        float a = gcn_b[e];
        #pragma unroll
        for (int k = 0; k < 64; ++k) a = fmaf(sAgg[m][k], sWg[k][e], a);
        a = fmaxf(a, 0.0f);
        sFus[m][e] = m_act[((size_t)(b * MM + m)) * EE + e] + a;
    }
    __syncthreads();

    if (t < 64) {
        float mn = 0.0f, mx = -INFINITY;
        #pragma unroll
        for (int m = 0; m < MM; ++m) { float v = sFus[m][t]; mn += v; mx = fmaxf(mx, v); }
        mn *= (1.0f / 16.0f);
        sFeats[t] = mn; sFeats[64 + t] = mx; sFeats[128 + t] = mn; sFeats[192 + t] = mx;
    }
    __syncthreads();

    {
        float p = 0.0f;
        #pragma unroll 8
        for (int kk = 0; kk < 64; ++kk) {
            int k = mq * 64 + kk;
            p = fmaf(sFeats[k], pna_W1[(size_t)k * 64 + e], p);
        }
        sPart[mq][e] = p;
    }
    __syncthreads();
    if (t < 64) sH1[t] = fmaxf(pna_b1[t] + sPart[0][t] + sPart[1][t] + sPart[2][t] + sPart[3][t], 0.0f);
    __syncthreads();

    {
        float p = 0.0f;
        #pragma unroll
        for (int kk = 0; kk < 16; ++kk) {
            int k = mq * 16 + kk;
            p = fmaf(sH1[k], pna_W2[(size_t)k * 64 + e], p);
        }
        sPart[mq][e] = p;
    }
    __syncthreads();
    if (t < 64) sH2[t] = fmaxf(pna_b2[t] + sPart[0][t] + sPart[1][t] + sPart[2][t] + sPart[3][t], 0.0f);
    __syncthreads();

    {
        float p = 0.0f;
        #pragma unroll
        for (int kk = 0; kk < 16; ++kk) {
            int k = mq * 16 + kk;
            p = fmaf(sH2[k], pna_W3[(size_t)k * 64 + e], p);
        }
        sPart[mq][e] = p;
    }
    __syncthreads();
    if (t < 64) sGrp[t] = pna_b3[t] + sPart[0][t] + sPart[1][t] + sPart[2][t] + sPart[3][t];
    __syncthreads();

    if (t < 8) {
        float a = pred_b1[t];
        for (int k = 0; k < 192; ++k) {
            float cv = (k < 64) ? sGrp[k] * sActe[k]
                                : ((k < 128) ? sGrp[k - 64] : sActe[k - 128]);
            a = fmaf(cv, pred_W1[k * 8 + t], a);
        }
        sHH[t] = fmaxf(a, 0.0f);
    }
    __syncthreads();
    if (t == 0) {
        float y = pred_b2[0];
        #pragma unroll
        for (int j = 0; j < 8; ++j) y = fmaf(sHH[j], pred_W2[j], y);
        out[b] = 1.0f / (1.0f + expf(-y));
    }
}

extern "C" void kernel_launch(void* const* d_in, const int* in_sizes, int n_in,
                              void* d_out, int out_size, void* d_ws, size_t ws_size,
                              hipStream_t stream) {
    const int*   members    = (const int*)d_in[0];
    const int*   neighbors  = (const int*)d_in[1];
    const int*   act_inputs = (const int*)d_in[2];
    const int*   act_seqs   = (const int*)d_in[3];
    const float* act_table  = (const float*)d_in[4];
    const float* user_table = (const float*)d_in[5];
    const float* W_ih       = (const float*)d_in[6];
    const float* W_hh       = (const float*)d_in[7];
    const float* b_ih       = (const float*)d_in[8];
    const float* b_hh       = (const float*)d_in[9];
    const float* gcn_W      = (const float*)d_in[10];
    const float* gcn_b      = (const float*)d_in[11];
    const float* pna_W1     = (const float*)d_in[12];
    const float* pna_b1     = (const float*)d_in[13];
    const float* pna_W2     = (const float*)d_in[14];
    const float* pna_b2     = (const float*)d_in[15];
    const float* pna_W3     = (const float*)d_in[16];
    const float* pna_b3     = (const float*)d_in[17];
    const float* pred_W1    = (const float*)d_in[18];
    const float* pred_b1    = (const float*)d_in[19];
    const float* pred_W2    = (const float*)d_in[20];
    const float* pred_b2    = (const float*)d_in[21];

    float*          m_act  = (float*)d_ws;                         // 4 MB
    unsigned short* act_bf = (unsigned short*)((char*)d_ws + (size_t)BB * MM * EE * 4);  // 12.8 MB

    cvt_table<<<dim3((NACT * EE / 8 + 255) / 256), dim3(256), 0, stream>>>(
        act_table, (unsigned*)act_bf);

    lstm_mfma<<<dim3(512), dim3(256), 0, stream>>>(
        act_seqs, act_bf, W_ih, W_hh, b_ih, b_hh, m_act);

    post_kernel<<<dim3(BB), dim3(256), 0, stream>>>(
        members, neighbors, act_inputs, act_table, user_table,
        gcn_W, gcn_b, pna_W1, pna_b1, pna_W2, pna_b2, pna_W3, pna_b3,
        pred_W1, pred_b1, pred_W2, pred_b2, m_act, (float*)d_out);
}